// Round 1
// baseline (250.675 us; speedup 1.0000x reference)
//
#include <hip/hip_runtime.h>

typedef float f32x4 __attribute__((ext_vector_type(4)));
typedef short bf16x8 __attribute__((ext_vector_type(8)));

#define NB 8
#define NH 16
#define NSEQ 1024
#define NP 64
#define NKV 1088
#define NC 1024
#define NHD 64

__device__ __forceinline__ unsigned short f2bf(float f) {
  unsigned int u = __builtin_bit_cast(unsigned int, f);
  u += 0x7fffu + ((u >> 16) & 1u);  // RNE
  return (unsigned short)(u >> 16);
}

__device__ __forceinline__ void gload16(const void* g, void* l) {
  __builtin_amdgcn_global_load_lds((const __attribute__((address_space(1))) void*)g,
                                   (__attribute__((address_space(3))) void*)l, 16, 0, 0);
}

__device__ __forceinline__ f32x4 mfma16(bf16x8 a, bf16x8 b, f32x4 c) {
  return __builtin_amdgcn_mfma_f32_16x16x32_bf16(a, b, c, 0, 0, 0);
}

// ---------------- pack kernels ----------------
__global__ void pack_bf16(const float* __restrict__ src, unsigned short* __restrict__ dst, int n4) {
  int i = blockIdx.x * 256 + threadIdx.x;
  if (i < n4) {
    float4 v = ((const float4*)src)[i];
    ushort4 o;
    o.x = f2bf(v.x); o.y = f2bf(v.y); o.z = f2bf(v.z); o.w = f2bf(v.w);
    ((ushort4*)dst)[i] = o;
  }
}

// prompt [B,2,P,H,hd] f32 -> Kg prefix [B,H,p<64,hd]*a (bf16), Vt prefix [B,H,hd,p<64]*a (bf16)
__global__ void prefix_pack(const float* __restrict__ prompt, unsigned short* __restrict__ Kg,
                            unsigned short* __restrict__ Vt, const float* __restrict__ alpha) {
  int i = blockIdx.x * 256 + threadIdx.x;  // 131072 total
  float a = alpha[0];
  int d4 = i & 15, p = (i >> 4) & 63, h = (i >> 10) & 15, b = i >> 14;
  const float4 kv = *(const float4*)(prompt + ((((size_t)(b * 2 + 0) * NP + p) * NH + h) * NHD + d4 * 4));
  ushort4 ko;
  ko.x = f2bf(kv.x * a); ko.y = f2bf(kv.y * a); ko.z = f2bf(kv.z * a); ko.w = f2bf(kv.w * a);
  *(ushort4*)(Kg + (((size_t)(b * NH + h) * NKV + p) * NHD + d4 * 4)) = ko;
  const float4 vv = *(const float4*)(prompt + ((((size_t)(b * 2 + 1) * NP + p) * NH + h) * NHD + d4 * 4));
  size_t vbase = ((size_t)(b * NH + h) * NHD + d4 * 4) * NKV + p;
  Vt[vbase]            = f2bf(vv.x * a);
  Vt[vbase + NKV]      = f2bf(vv.y * a);
  Vt[vbase + 2 * NKV]  = f2bf(vv.z * a);
  Vt[vbase + 3 * NKV]  = f2bf(vv.w * a);
}

// ---------------- GEMM (B^T layout: out[m,c] = sum_k A[m,k]*Bw[c,k]) ----------------
// MODE 0: qkv epilogue (scatter to Q / K(+64) / V^T(+64) with scales)
// MODE 1: proj epilogue (f32 out + bias)
template <int MODE>
__global__ __launch_bounds__(256, 2)
void gemm_bt(const unsigned short* __restrict__ A, const unsigned short* __restrict__ Bw, int K,
             unsigned short* __restrict__ Qg, unsigned short* __restrict__ Kg,
             unsigned short* __restrict__ Vt,
             const float* __restrict__ alphap, const float* __restrict__ halfp,
             float* __restrict__ Cout, const float* __restrict__ bias) {
  __shared__ __align__(16) unsigned short ldsA[128 * 32];
  __shared__ __align__(16) unsigned short ldsB[128 * 32];
  const int tid = threadIdx.x, lane = tid & 63, wv = tid >> 6;
  const int wr = wv >> 1, wc = wv & 1;
  const int lg = lane >> 4, lr = lane & 15;
  const int bx = blockIdx.x, by = blockIdx.y;

  f32x4 acc[4][4] = {};

  // staging: 512 chunks of 16B per 128x32 tile; chunk q -> row=q>>2, col-chunk c=q&3,
  // source col-chunk swizzled c^(row&3); LDS kept linear (global_load_lds constraint)
  const int r0 = tid >> 2, c0 = tid & 3;
  const int swz = c0 ^ (r0 & 3);  // (r0+64)&3 == r0&3
  const unsigned short* Ag0 = A + (size_t)(bx * 128 + r0) * K + swz * 8;
  const unsigned short* Ag1 = Ag0 + (size_t)64 * K;
  const unsigned short* Bg0 = Bw + (size_t)(by * 128 + r0) * K + swz * 8;
  const unsigned short* Bg1 = Bg0 + (size_t)64 * K;
  unsigned short* la0 = ldsA + wv * 512;
  unsigned short* la1 = ldsA + 2048 + wv * 512;
  unsigned short* lb0 = ldsB + wv * 512;
  unsigned short* lb1 = ldsB + 2048 + wv * 512;

  for (int k0 = 0; k0 < K; k0 += 32) {
    __syncthreads();
    gload16(Ag0 + k0, la0);
    gload16(Ag1 + k0, la1);
    gload16(Bg0 + k0, lb0);
    gload16(Bg1 + k0, lb1);
    __syncthreads();
    bf16x8 af[4], bfm[4];
#pragma unroll
    for (int m = 0; m < 4; ++m) {
      const int row = wr * 64 + m * 16 + lr;
      const int cc = lg ^ (row & 3);
      af[m] = *(const bf16x8*)(ldsA + row * 32 + cc * 8);
    }
#pragma unroll
    for (int n = 0; n < 4; ++n) {
      const int row = wc * 64 + n * 16 + lr;
      const int cc = lg ^ (row & 3);
      bfm[n] = *(const bf16x8*)(ldsB + row * 32 + cc * 8);
    }
#pragma unroll
    for (int m = 0; m < 4; ++m)
#pragma unroll
      for (int n = 0; n < 4; ++n)
        acc[m][n] = mfma16(af[m], bfm[n], acc[m][n]);
  }

  if constexpr (MODE == 0) {
    const int slot = (by * 128) >> 10;     // 0=q 1=k 2=v (col tiles never straddle slots)
    const int csIn = (by * 128) & 1023;
    const float sc = (slot == 0) ? 0.125f : (alphap[0] * halfp[0]);
#pragma unroll
    for (int m = 0; m < 4; ++m) {
      const int grow0 = bx * 128 + wr * 64 + m * 16 + lg * 4;
#pragma unroll
      for (int n = 0; n < 4; ++n) {
        const int gcol = csIn + wc * 64 + n * 16 + lr;
        const int h = gcol >> 6, d = gcol & 63;
#pragma unroll
        for (int j = 0; j < 4; ++j) {
          const int grow = grow0 + j;
          const int b = grow >> 10, nn = grow & 1023;
          const unsigned short u = f2bf(acc[m][n][j] * sc);
          if (slot == 0)      Qg[(((size_t)b * NH + h) * NSEQ + nn) * NHD + d] = u;
          else if (slot == 1) Kg[(((size_t)b * NH + h) * NKV + NP + nn) * NHD + d] = u;
          else                Vt[(((size_t)b * NH + h) * NHD + d) * NKV + NP + nn] = u;
        }
      }
    }
  } else {
#pragma unroll
    for (int m = 0; m < 4; ++m) {
      const int grow0 = bx * 128 + wr * 64 + m * 16 + lg * 4;
#pragma unroll
      for (int n = 0; n < 4; ++n) {
        const int gcol = by * 128 + wc * 64 + n * 16 + lr;
        const float bb = bias[gcol];
#pragma unroll
        for (int j = 0; j < 4; ++j)
          Cout[(size_t)(grow0 + j) * NC + gcol] = acc[m][n][j] + bb;
      }
    }
  }
}

// ---------------- flash attention ----------------
// grid (8 q-tiles, 128 bh); 4 waves x 32 q-rows; KV tiles of 64
__global__ __launch_bounds__(256, 2)
void attn_fwd(const unsigned short* __restrict__ Qg, const unsigned short* __restrict__ Kg,
              const unsigned short* __restrict__ Vt, unsigned short* __restrict__ Oat) {
  __shared__ __align__(16) unsigned short Klds[64 * 64];
  __shared__ __align__(16) unsigned short Vlds[64 * 64];   // V^T: rows d, cols kv
  __shared__ __align__(16) unsigned short Plds[4 * 32 * 64];
  const int tid = threadIdx.x, lane = tid & 63, wv = tid >> 6;
  const int bh = blockIdx.y;
  const int q0 = blockIdx.x * 128;
  const int lg = lane >> 4, lr = lane & 15;

  // Q fragments in registers (scaled by 0.125 already)
  bf16x8 aq[2][2];
#pragma unroll
  for (int m = 0; m < 2; ++m)
#pragma unroll
    for (int kk = 0; kk < 2; ++kk)
      aq[m][kk] = *(const bf16x8*)(Qg + ((size_t)bh * NSEQ + q0 + wv * 32 + m * 16 + lr) * NHD + kk * 32 + lg * 8);

  f32x4 oac[2][4] = {};
  float mrun[2][4], lrun[2][4];
#pragma unroll
  for (int m = 0; m < 2; ++m)
#pragma unroll
    for (int j = 0; j < 4; ++j) { mrun[m][j] = -1e30f; lrun[m][j] = 0.f; }

  const int kr0 = tid >> 3, kc = tid & 7;
  const int sw = kc ^ (kr0 & 7);  // (kr0+32)&7 == kr0&7
  const unsigned short* Kg0 = Kg + ((size_t)bh * NKV + kr0) * NHD + sw * 8;
  const unsigned short* Vg0 = Vt + ((size_t)bh * NHD + kr0) * NKV + sw * 8;
  unsigned short* lk0 = Klds + wv * 512;
  unsigned short* lk1 = Klds + 2048 + wv * 512;
  unsigned short* lv0 = Vlds + wv * 512;
  unsigned short* lv1 = Vlds + 2048 + wv * 512;
  unsigned short* Pw = Plds + wv * 2048;

  for (int t = 0; t < 17; ++t) {
    __syncthreads();
    gload16(Kg0 + t * 4096, lk0);
    gload16(Kg0 + t * 4096 + (size_t)32 * NHD, lk1);
    gload16(Vg0 + t * 64, lv0);
    gload16(Vg0 + t * 64 + (size_t)32 * NKV, lv1);
    __syncthreads();

    // S = Q K^T for this wave's 32 rows x 64 kv
    f32x4 sa[2][4] = {};
#pragma unroll
    for (int kk = 0; kk < 2; ++kk) {
      bf16x8 bk[4];
#pragma unroll
      for (int n = 0; n < 4; ++n) {
        const int row = n * 16 + lr;
        const int cc = (kk * 4 + lg) ^ (row & 7);
        bk[n] = *(const bf16x8*)(Klds + row * 64 + cc * 8);
      }
#pragma unroll
      for (int m = 0; m < 2; ++m)
#pragma unroll
        for (int n = 0; n < 4; ++n)
          sa[m][n] = mfma16(aq[m][kk], bk[n], sa[m][n]);
    }

    // online softmax (rows live in 16-lane groups; butterfly over masks 1,2,4,8)
#pragma unroll
    for (int m = 0; m < 2; ++m) {
      float mx[4], esc[4];
#pragma unroll
      for (int j = 0; j < 4; ++j) {
        float tmx = fmaxf(fmaxf(sa[m][0][j], sa[m][1][j]), fmaxf(sa[m][2][j], sa[m][3][j]));
#pragma unroll
        for (int msk = 1; msk < 16; msk <<= 1) tmx = fmaxf(tmx, __shfl_xor(tmx, msk));
        mx[j] = fmaxf(mrun[m][j], tmx);
        esc[j] = __expf(mrun[m][j] - mx[j]);
        mrun[m][j] = mx[j];
      }
#pragma unroll
      for (int n = 0; n < 4; ++n)
#pragma unroll
        for (int j = 0; j < 4; ++j)
          sa[m][n][j] = __expf(sa[m][n][j] - mx[j]);
#pragma unroll
      for (int j = 0; j < 4; ++j) {
        float s = sa[m][0][j] + sa[m][1][j] + sa[m][2][j] + sa[m][3][j];
#pragma unroll
        for (int msk = 1; msk < 16; msk <<= 1) s += __shfl_xor(s, msk);
        lrun[m][j] = lrun[m][j] * esc[j] + s;
      }
#pragma unroll
      for (int df = 0; df < 4; ++df)
#pragma unroll
        for (int j = 0; j < 4; ++j)
          oac[m][df][j] *= esc[j];
      // write P (bf16) to per-wave LDS, XOR-swizzled on 16B chunks
#pragma unroll
      for (int n = 0; n < 4; ++n)
#pragma unroll
        for (int j = 0; j < 4; ++j) {
          const int row = m * 16 + lg * 4 + j;
          const int col = n * 16 + lr;
          Pw[row * 64 + (col ^ ((row & 7) << 3))] = f2bf(sa[m][n][j]);
        }
    }

    // O += P @ V  (A = P from LDS, B = V^T rows contiguous in kv)
#pragma unroll
    for (int kk = 0; kk < 2; ++kk) {
      bf16x8 bv[4], ap[2];
#pragma unroll
      for (int df = 0; df < 4; ++df) {
        const int d = df * 16 + lr;
        const int cc = (kk * 4 + lg) ^ (d & 7);
        bv[df] = *(const bf16x8*)(Vlds + d * 64 + cc * 8);
      }
#pragma unroll
      for (int m = 0; m < 2; ++m) {
        const int q = m * 16 + lr;
        const int cc = (kk * 4 + lg) ^ (q & 7);
        ap[m] = *(const bf16x8*)(Pw + q * 64 + cc * 8);
      }
#pragma unroll
      for (int m = 0; m < 2; ++m)
#pragma unroll
        for (int df = 0; df < 4; ++df)
          oac[m][df] = mfma16(ap[m], bv[df], oac[m][df]);
    }
  }

  const int b = bh >> 4, h = bh & 15;
#pragma unroll
  for (int m = 0; m < 2; ++m) {
#pragma unroll
    for (int j = 0; j < 4; ++j) {
      const float inv = 1.f / lrun[m][j];
      const int row = q0 + wv * 32 + m * 16 + lg * 4 + j;
#pragma unroll
      for (int df = 0; df < 4; ++df) {
        const int col = h * 64 + df * 16 + lr;
        Oat[((size_t)b * NSEQ + row) * NC + col] = f2bf(oac[m][df][j] * inv);
      }
    }
  }
}

// ---------------- launch ----------------
extern "C" void kernel_launch(void* const* d_in, const int* in_sizes, int n_in,
                              void* d_out, int out_size, void* d_ws, size_t ws_size,
                              hipStream_t stream) {
  const float* x      = (const float*)d_in[0];
  const float* prompt = (const float*)d_in[1];
  const float* alpha  = (const float*)d_in[2];
  const float* halfa  = (const float*)d_in[3];
  const float* Wqkv   = (const float*)d_in[4];
  const float* Wproj  = (const float*)d_in[5];
  const float* bproj  = (const float*)d_in[6];
  float* out = (float*)d_out;

  unsigned short* ws    = (unsigned short*)d_ws;
  unsigned short* x_bf  = ws;                                  // 8192*1024
  unsigned short* w_bf  = x_bf + (size_t)8192 * 1024;          // 3072*1024
  unsigned short* wp_bf = w_bf + (size_t)3072 * 1024;          // 1024*1024
  unsigned short* Qg    = wp_bf + (size_t)1024 * 1024;         // B*H*N*hd
  unsigned short* Kg    = Qg + (size_t)NB * NH * NSEQ * NHD;   // B*H*KV*hd
  unsigned short* Vt    = Kg + (size_t)NB * NH * NKV * NHD;    // B*H*hd*KV (transposed)
  unsigned short* Oat   = Vt + (size_t)NB * NH * NKV * NHD;    // B*N*C

  pack_bf16<<<8192, 256, 0, stream>>>(x, x_bf, 2097152);
  pack_bf16<<<3072, 256, 0, stream>>>(Wqkv, w_bf, 786432);
  pack_bf16<<<1024, 256, 0, stream>>>(Wproj, wp_bf, 262144);
  prefix_pack<<<512, 256, 0, stream>>>(prompt, Kg, Vt, alpha);

  gemm_bt<0><<<dim3(64, 24), 256, 0, stream>>>(x_bf, w_bf, 1024, Qg, Kg, Vt, alpha, halfa,
                                               nullptr, nullptr);
  attn_fwd<<<dim3(8, 128), 256, 0, stream>>>(Qg, Kg, Vt, Oat);
  gemm_bt<1><<<dim3(64, 8), 256, 0, stream>>>(Oat, wp_bf, 1024, nullptr, nullptr, nullptr,
                                              nullptr, nullptr, out, bproj);
}

// Round 2
// 190.739 us; speedup vs baseline: 1.3142x; 1.3142x over previous
//
#include <hip/hip_runtime.h>

typedef float f32x4 __attribute__((ext_vector_type(4)));
typedef short bf16x8 __attribute__((ext_vector_type(8)));

#define NB 8
#define NH 16
#define NSEQ 1024
#define NP 64
#define NKV 1088
#define NC 1024
#define NHD 64

__device__ __forceinline__ unsigned short f2bf(float f) {
  unsigned int u = __builtin_bit_cast(unsigned int, f);
  u += 0x7fffu + ((u >> 16) & 1u);  // RNE
  return (unsigned short)(u >> 16);
}

__device__ __forceinline__ void gload16(const void* g, void* l) {
  __builtin_amdgcn_global_load_lds((const __attribute__((address_space(1))) void*)g,
                                   (__attribute__((address_space(3))) void*)l, 16, 0, 0);
}

__device__ __forceinline__ f32x4 mfma16(bf16x8 a, bf16x8 b, f32x4 c) {
  return __builtin_amdgcn_mfma_f32_16x16x32_bf16(a, b, c, 0, 0, 0);
}

// ---------------- pack kernels ----------------
__global__ void pack_bf16(const float* __restrict__ src, unsigned short* __restrict__ dst, int n4) {
  int i = blockIdx.x * 256 + threadIdx.x;
  if (i < n4) {
    float4 v = ((const float4*)src)[i];
    ushort4 o;
    o.x = f2bf(v.x); o.y = f2bf(v.y); o.z = f2bf(v.z); o.w = f2bf(v.w);
    ((ushort4*)dst)[i] = o;
  }
}

// prompt [B,2,P,H,hd] f32 -> Kg prefix [B,H,p<64,hd]*a (bf16), Vt prefix [B,H,hd,p<64]*a (bf16)
__global__ void prefix_pack(const float* __restrict__ prompt, unsigned short* __restrict__ Kg,
                            unsigned short* __restrict__ Vt, const float* __restrict__ alpha) {
  int i = blockIdx.x * 256 + threadIdx.x;  // 131072 total
  float a = alpha[0];
  int d4 = i & 15, p = (i >> 4) & 63, h = (i >> 10) & 15, b = i >> 14;
  const float4 kv = *(const float4*)(prompt + ((((size_t)(b * 2 + 0) * NP + p) * NH + h) * NHD + d4 * 4));
  ushort4 ko;
  ko.x = f2bf(kv.x * a); ko.y = f2bf(kv.y * a); ko.z = f2bf(kv.z * a); ko.w = f2bf(kv.w * a);
  *(ushort4*)(Kg + (((size_t)(b * NH + h) * NKV + p) * NHD + d4 * 4)) = ko;
  const float4 vv = *(const float4*)(prompt + ((((size_t)(b * 2 + 1) * NP + p) * NH + h) * NHD + d4 * 4));
  size_t vbase = ((size_t)(b * NH + h) * NHD + d4 * 4) * NKV + p;
  Vt[vbase]            = f2bf(vv.x * a);
  Vt[vbase + NKV]      = f2bf(vv.y * a);
  Vt[vbase + 2 * NKV]  = f2bf(vv.z * a);
  Vt[vbase + 3 * NKV]  = f2bf(vv.w * a);
}

// ---------------- GEMM (B^T layout: out[m,c] = sum_k A[m,k]*Bw[c,k]) ----------------
template <int MODE>
__global__ __launch_bounds__(256, 2)
void gemm_bt(const unsigned short* __restrict__ A, const unsigned short* __restrict__ Bw, int K,
             unsigned short* __restrict__ Qg, unsigned short* __restrict__ Kg,
             unsigned short* __restrict__ Vt,
             const float* __restrict__ alphap, const float* __restrict__ halfp,
             float* __restrict__ Cout, const float* __restrict__ bias) {
  __shared__ __align__(16) unsigned short ldsA[128 * 32];
  __shared__ __align__(16) unsigned short ldsB[128 * 32];
  const int tid = threadIdx.x, lane = tid & 63, wv = tid >> 6;
  const int wr = wv >> 1, wc = wv & 1;
  const int lg = lane >> 4, lr = lane & 15;
  const int bx = blockIdx.x, by = blockIdx.y;

  f32x4 acc[4][4] = {};

  const int r0 = tid >> 2, c0 = tid & 3;
  const int swz = c0 ^ (r0 & 3);
  const unsigned short* Ag0 = A + (size_t)(bx * 128 + r0) * K + swz * 8;
  const unsigned short* Ag1 = Ag0 + (size_t)64 * K;
  const unsigned short* Bg0 = Bw + (size_t)(by * 128 + r0) * K + swz * 8;
  const unsigned short* Bg1 = Bg0 + (size_t)64 * K;
  unsigned short* la0 = ldsA + wv * 512;
  unsigned short* la1 = ldsA + 2048 + wv * 512;
  unsigned short* lb0 = ldsB + wv * 512;
  unsigned short* lb1 = ldsB + 2048 + wv * 512;

  for (int k0 = 0; k0 < K; k0 += 32) {
    __syncthreads();
    gload16(Ag0 + k0, la0);
    gload16(Ag1 + k0, la1);
    gload16(Bg0 + k0, lb0);
    gload16(Bg1 + k0, lb1);
    __syncthreads();
    bf16x8 af[4], bfm[4];
#pragma unroll
    for (int m = 0; m < 4; ++m) {
      const int row = wr * 64 + m * 16 + lr;
      const int cc = lg ^ (row & 3);
      af[m] = *(const bf16x8*)(ldsA + row * 32 + cc * 8);
    }
#pragma unroll
    for (int n = 0; n < 4; ++n) {
      const int row = wc * 64 + n * 16 + lr;
      const int cc = lg ^ (row & 3);
      bfm[n] = *(const bf16x8*)(ldsB + row * 32 + cc * 8);
    }
#pragma unroll
    for (int m = 0; m < 4; ++m)
#pragma unroll
      for (int n = 0; n < 4; ++n)
        acc[m][n] = mfma16(af[m], bfm[n], acc[m][n]);
  }

  if constexpr (MODE == 0) {
    const int slot = (by * 128) >> 10;
    const int csIn = (by * 128) & 1023;
    // Q gets softmax scale folded in base-2 domain: 0.125 * log2(e)
    const float sc = (slot == 0) ? 0.18033688011112042f : (alphap[0] * halfp[0]);
#pragma unroll
    for (int m = 0; m < 4; ++m) {
      const int grow0 = bx * 128 + wr * 64 + m * 16 + lg * 4;
#pragma unroll
      for (int n = 0; n < 4; ++n) {
        const int gcol = csIn + wc * 64 + n * 16 + lr;
        const int h = gcol >> 6, d = gcol & 63;
#pragma unroll
        for (int j = 0; j < 4; ++j) {
          const int grow = grow0 + j;
          const int b = grow >> 10, nn = grow & 1023;
          const unsigned short u = f2bf(acc[m][n][j] * sc);
          if (slot == 0)      Qg[(((size_t)b * NH + h) * NSEQ + nn) * NHD + d] = u;
          else if (slot == 1) Kg[(((size_t)b * NH + h) * NKV + NP + nn) * NHD + d] = u;
          else                Vt[(((size_t)b * NH + h) * NHD + d) * NKV + NP + nn] = u;
        }
      }
    }
  } else {
#pragma unroll
    for (int m = 0; m < 4; ++m) {
      const int grow0 = bx * 128 + wr * 64 + m * 16 + lg * 4;
#pragma unroll
      for (int n = 0; n < 4; ++n) {
        const int gcol = by * 128 + wc * 64 + n * 16 + lr;
        const float bb = bias[gcol];
#pragma unroll
        for (int j = 0; j < 4; ++j)
          Cout[(size_t)(grow0 + j) * NC + gcol] = acc[m][n][j] + bb;
      }
    }
  }
}

// ---------------- flash attention (swapped QK^T, defer-max, 2-deep pipeline) ----------------
// flat grid 1024: bh = id&127 (XCD locality: bh%8 -> same XCD), qtile = id>>7
__global__ __launch_bounds__(256, 3)
void attn_fwd(const unsigned short* __restrict__ Qg, const unsigned short* __restrict__ Kg,
              const unsigned short* __restrict__ Vt, unsigned short* __restrict__ Oat) {
  __shared__ __align__(16) unsigned short Klds[2][64 * 64];
  __shared__ __align__(16) unsigned short Vlds[2][64 * 64];
  __shared__ __align__(16) unsigned short Plds[4 * 32 * 64];
  const int tid = threadIdx.x, lane = tid & 63, wv = tid >> 6;
  const int bh = blockIdx.x & 127;
  const int q0 = (blockIdx.x >> 7) * 128;
  const int lg = lane >> 4, lr = lane & 15;

  // Q as B-operand frags: lane holds Q[q = wv*32+nq*16+lr][k = kk*32+lg*8 ..+8]
  bf16x8 bq[2][2];
#pragma unroll
  for (int nq = 0; nq < 2; ++nq)
#pragma unroll
    for (int kk = 0; kk < 2; ++kk)
      bq[nq][kk] = *(const bf16x8*)(Qg + ((size_t)bh * NSEQ + q0 + wv * 32 + nq * 16 + lr) * NHD + kk * 32 + lg * 8);

  f32x4 oac[2][4] = {};
  float mrun[2] = {-1e30f, -1e30f};
  float lrun[2] = {0.f, 0.f};

  const int kr0 = tid >> 3, kc = tid & 7;
  const int sw = kc ^ (kr0 & 7);
  const unsigned short* Kgp = Kg + ((size_t)bh * NKV + kr0) * NHD + sw * 8;
  const unsigned short* Vgp = Vt + ((size_t)bh * NHD + kr0) * NKV + sw * 8;
  unsigned short* Pw = Plds + wv * 2048;

#define STAGE(t, bsel)                                                      \
  do {                                                                      \
    unsigned short* kb = &Klds[bsel][0] + wv * 512;                         \
    unsigned short* vb = &Vlds[bsel][0] + wv * 512;                         \
    gload16(Kgp + (size_t)(t) * 4096, kb);                                  \
    gload16(Kgp + (size_t)(t) * 4096 + 32 * NHD, kb + 2048);                \
    gload16(Vgp + (size_t)(t) * 64, vb);                                    \
    gload16(Vgp + (size_t)(t) * 64 + (size_t)32 * NKV, vb + 2048);          \
  } while (0)

  STAGE(0, 0);
  asm volatile("s_waitcnt vmcnt(0)" ::: "memory");
  __builtin_amdgcn_s_barrier();

  for (int t = 0; t < 17; ++t) {
    const int b = t & 1;
    if (t < 16) STAGE(t + 1, b ^ 1);

    // S^T = K Q^T : sa[mk][nq], lane holds k = mk*16+lg*4+j for q = nq*16+lr
    f32x4 sa[4][2] = {};
    __builtin_amdgcn_s_setprio(1);
#pragma unroll
    for (int kk = 0; kk < 2; ++kk) {
      bf16x8 ak[4];
#pragma unroll
      for (int mk = 0; mk < 4; ++mk) {
        const int row = mk * 16 + lr;
        const int cc = (kk * 4 + lg) ^ (row & 7);
        ak[mk] = *(const bf16x8*)(&Klds[b][0] + row * 64 + cc * 8);
      }
#pragma unroll
      for (int mk = 0; mk < 4; ++mk)
#pragma unroll
        for (int nq = 0; nq < 2; ++nq)
          sa[mk][nq] = mfma16(ak[mk], bq[nq][kk], sa[mk][nq]);
    }
    __builtin_amdgcn_s_setprio(0);

    // row-max per q (lane owns q = nq*16+lr across lg quarter of k)
    float tmx[2];
#pragma unroll
    for (int nq = 0; nq < 2; ++nq) {
      f32x4 m4 = sa[0][nq];
#pragma unroll
      for (int mk = 1; mk < 4; ++mk)
#pragma unroll
        for (int j = 0; j < 4; ++j) m4[j] = fmaxf(m4[j], sa[mk][nq][j]);
      float tm = fmaxf(fmaxf(m4[0], m4[1]), fmaxf(m4[2], m4[3]));
      tm = fmaxf(tm, __shfl_xor(tm, 16));
      tm = fmaxf(tm, __shfl_xor(tm, 32));
      tmx[nq] = tm;
    }
    // defer-max (T13): only rescale when max grows > 8 (log2 domain)
    const bool upd = !__all((tmx[0] <= mrun[0] + 8.f) && (tmx[1] <= mrun[1] + 8.f));
    if (upd) {
      const float nm0 = fmaxf(mrun[0], tmx[0]);
      const float nm1 = fmaxf(mrun[1], tmx[1]);
      const float e0 = __builtin_amdgcn_exp2f(mrun[0] - nm0);
      const float e1 = __builtin_amdgcn_exp2f(mrun[1] - nm1);
      mrun[0] = nm0; mrun[1] = nm1;
      lrun[0] *= e0; lrun[1] *= e1;
#pragma unroll
      for (int m = 0; m < 2; ++m)
#pragma unroll
        for (int j = 0; j < 4; ++j) {
          const float fe = __shfl(m ? e1 : e0, lg * 4 + j, 16);
#pragma unroll
          for (int df = 0; df < 4; ++df) oac[m][df][j] *= fe;
        }
    }
    // P = 2^(S - m), sum, packed store to per-wave LDS (chunk-XOR swizzle)
#pragma unroll
    for (int nq = 0; nq < 2; ++nq) {
#pragma unroll
      for (int mk = 0; mk < 4; ++mk)
#pragma unroll
        for (int j = 0; j < 4; ++j)
          sa[mk][nq][j] = __builtin_amdgcn_exp2f(sa[mk][nq][j] - mrun[nq]);
      f32x4 s4 = sa[0][nq];
#pragma unroll
      for (int mk = 1; mk < 4; ++mk)
#pragma unroll
        for (int j = 0; j < 4; ++j) s4[j] += sa[mk][nq][j];
      float s = (s4[0] + s4[1]) + (s4[2] + s4[3]);
      s += __shfl_xor(s, 16);
      s += __shfl_xor(s, 32);
      lrun[nq] += s;
      const int q = nq * 16 + lr;
#pragma unroll
      for (int mk = 0; mk < 4; ++mk) {
        const int c = mk * 2 + (lg >> 1);
        uint2 uu;
        uu.x = (unsigned)f2bf(sa[mk][nq][0]) | ((unsigned)f2bf(sa[mk][nq][1]) << 16);
        uu.y = (unsigned)f2bf(sa[mk][nq][2]) | ((unsigned)f2bf(sa[mk][nq][3]) << 16);
        *(uint2*)(Pw + q * 64 + ((c ^ (q & 7)) << 3) + (lg & 1) * 4) = uu;
      }
    }

    // O += P V : A = P rows q (16B contiguous after swizzle), B = V^T rows d
    __builtin_amdgcn_s_setprio(1);
#pragma unroll
    for (int kk = 0; kk < 2; ++kk) {
      bf16x8 bv[4], ap[2];
#pragma unroll
      for (int df = 0; df < 4; ++df) {
        const int d = df * 16 + lr;
        const int cc = (kk * 4 + lg) ^ (d & 7);
        bv[df] = *(const bf16x8*)(&Vlds[b][0] + d * 64 + cc * 8);
      }
#pragma unroll
      for (int m = 0; m < 2; ++m) {
        const int q = m * 16 + lr;
        const int pos = (kk * 4 + lg) ^ (q & 7);
        ap[m] = *(const bf16x8*)(Pw + q * 64 + pos * 8);
      }
#pragma unroll
      for (int m = 0; m < 2; ++m)
#pragma unroll
        for (int df = 0; df < 4; ++df)
          oac[m][df] = mfma16(ap[m], bv[df], oac[m][df]);
    }
    __builtin_amdgcn_s_setprio(0);

    asm volatile("s_waitcnt vmcnt(0)" ::: "memory");
    __builtin_amdgcn_s_barrier();
  }
#undef STAGE

  const int bidx = bh >> 4, h = bh & 15;
  const float l0 = 1.f / lrun[0], l1 = 1.f / lrun[1];
#pragma unroll
  for (int m = 0; m < 2; ++m) {
#pragma unroll
    for (int j = 0; j < 4; ++j) {
      const float fi = __shfl(m ? l1 : l0, lg * 4 + j, 16);
      const int row = q0 + wv * 32 + m * 16 + lg * 4 + j;
#pragma unroll
      for (int df = 0; df < 4; ++df) {
        const int col = h * 64 + df * 16 + lr;
        Oat[((size_t)bidx * NSEQ + row) * NC + col] = f2bf(oac[m][df][j] * fi);
      }
    }
  }
}

// ---------------- launch ----------------
extern "C" void kernel_launch(void* const* d_in, const int* in_sizes, int n_in,
                              void* d_out, int out_size, void* d_ws, size_t ws_size,
                              hipStream_t stream) {
  const float* x      = (const float*)d_in[0];
  const float* prompt = (const float*)d_in[1];
  const float* alpha  = (const float*)d_in[2];
  const float* halfa  = (const float*)d_in[3];
  const float* Wqkv   = (const float*)d_in[4];
  const float* Wproj  = (const float*)d_in[5];
  const float* bproj  = (const float*)d_in[6];
  float* out = (float*)d_out;

  unsigned short* ws    = (unsigned short*)d_ws;
  unsigned short* x_bf  = ws;
  unsigned short* w_bf  = x_bf + (size_t)8192 * 1024;
  unsigned short* wp_bf = w_bf + (size_t)3072 * 1024;
  unsigned short* Qg    = wp_bf + (size_t)1024 * 1024;
  unsigned short* Kg    = Qg + (size_t)NB * NH * NSEQ * NHD;
  unsigned short* Vt    = Kg + (size_t)NB * NH * NKV * NHD;
  unsigned short* Oat   = Vt + (size_t)NB * NH * NKV * NHD;

  pack_bf16<<<8192, 256, 0, stream>>>(x, x_bf, 2097152);
  pack_bf16<<<3072, 256, 0, stream>>>(Wqkv, w_bf, 786432);
  pack_bf16<<<1024, 256, 0, stream>>>(Wproj, wp_bf, 262144);
  prefix_pack<<<512, 256, 0, stream>>>(prompt, Kg, Vt, alpha);

  gemm_bt<0><<<dim3(64, 24), 256, 0, stream>>>(x_bf, w_bf, 1024, Qg, Kg, Vt, alpha, halfa,
                                               nullptr, nullptr);
  attn_fwd<<<1024, 256, 0, stream>>>(Qg, Kg, Vt, Oat);
  gemm_bt<1><<<dim3(64, 8), 256, 0, stream>>>(Oat, wp_bf, 1024, nullptr, nullptr, nullptr,
                                              nullptr, nullptr, out, bproj);
}

// Round 3
// 188.565 us; speedup vs baseline: 1.3294x; 1.0115x over previous
//
#include <hip/hip_runtime.h>

typedef float f32x4 __attribute__((ext_vector_type(4)));
typedef short bf16x8 __attribute__((ext_vector_type(8)));

#define NB 8
#define NH 16
#define NSEQ 1024
#define NP 64
#define NKV 1088
#define NC 1024
#define NHD 64

__device__ __forceinline__ unsigned short f2bf(float f) {
  unsigned int u = __builtin_bit_cast(unsigned int, f);
  u += 0x7fffu + ((u >> 16) & 1u);  // RNE
  return (unsigned short)(u >> 16);
}

__device__ __forceinline__ void gload16(const void* g, void* l) {
  __builtin_amdgcn_global_load_lds((const __attribute__((address_space(1))) void*)g,
                                   (__attribute__((address_space(3))) void*)l, 16, 0, 0);
}

__device__ __forceinline__ f32x4 mfma16(bf16x8 a, bf16x8 b, f32x4 c) {
  return __builtin_amdgcn_mfma_f32_16x16x32_bf16(a, b, c, 0, 0, 0);
}

// ---------------- pack kernels ----------------
__global__ void pack_bf16(const float* __restrict__ src, unsigned short* __restrict__ dst, int n4) {
  int i = blockIdx.x * 256 + threadIdx.x;
  if (i < n4) {
    float4 v = ((const float4*)src)[i];
    ushort4 o;
    o.x = f2bf(v.x); o.y = f2bf(v.y); o.z = f2bf(v.z); o.w = f2bf(v.w);
    ((ushort4*)dst)[i] = o;
  }
}

// prompt [B,2,P,H,hd] f32 -> Kg prefix [B,H,p<64,hd]*a (bf16), Vt prefix [B,H,hd,p<64]*a (bf16)
__global__ void prefix_pack(const float* __restrict__ prompt, unsigned short* __restrict__ Kg,
                            unsigned short* __restrict__ Vt, const float* __restrict__ alpha) {
  int i = blockIdx.x * 256 + threadIdx.x;  // 131072 total
  float a = alpha[0];
  int d4 = i & 15, p = (i >> 4) & 63, h = (i >> 10) & 15, b = i >> 14;
  const float4 kv = *(const float4*)(prompt + ((((size_t)(b * 2 + 0) * NP + p) * NH + h) * NHD + d4 * 4));
  ushort4 ko;
  ko.x = f2bf(kv.x * a); ko.y = f2bf(kv.y * a); ko.z = f2bf(kv.z * a); ko.w = f2bf(kv.w * a);
  *(ushort4*)(Kg + (((size_t)(b * NH + h) * NKV + p) * NHD + d4 * 4)) = ko;
  const float4 vv = *(const float4*)(prompt + ((((size_t)(b * 2 + 1) * NP + p) * NH + h) * NHD + d4 * 4));
  size_t vbase = ((size_t)(b * NH + h) * NHD + d4 * 4) * NKV + p;
  Vt[vbase]            = f2bf(vv.x * a);
  Vt[vbase + NKV]      = f2bf(vv.y * a);
  Vt[vbase + 2 * NKV]  = f2bf(vv.z * a);
  Vt[vbase + 3 * NKV]  = f2bf(vv.w * a);
}

// ---------------- GEMM (B^T layout: out[m,c] = sum_k A[m,k]*Bw[c,k]) ----------------
// BK=64, double-buffered LDS, counted-vmcnt 2-phase pipeline (T3-min + T4).
template <int MODE>
__global__ __launch_bounds__(256, 2)
void gemm_bt(const unsigned short* __restrict__ A, const unsigned short* __restrict__ Bw, int K,
             unsigned short* __restrict__ Qg, unsigned short* __restrict__ Kg,
             unsigned short* __restrict__ Vt,
             const float* __restrict__ alphap, const float* __restrict__ halfp,
             float* __restrict__ Cout, const float* __restrict__ bias) {
  __shared__ __align__(16) unsigned short ldsA[2][128 * 64];
  __shared__ __align__(16) unsigned short ldsB[2][128 * 64];
  const int tid = threadIdx.x, lane = tid & 63, wv = tid >> 6;
  const int wr = wv >> 1, wc = wv & 1;
  const int lg = lane >> 4, lr = lane & 15;
  const int bx = blockIdx.x, by = blockIdx.y;

  f32x4 acc[4][4] = {};

  // staging: tile 128 rows x 64 cols bf16 = 1024 16B-chunks; thread handles
  // chunks c = tid + 256*i. row = c>>3, col-chunk = c&7; global source
  // col-chunk swizzled (c&7)^(row&7); LDS linear (rule #21: inverse-swz source
  // + linear dest + swz read; XOR is an involution).
  const unsigned short* Ag[4];
  const unsigned short* Bg[4];
  int ldof[4];
#pragma unroll
  for (int i = 0; i < 4; ++i) {
    const int c = tid + 256 * i;
    const int row = c >> 3;
    const int gch = (c & 7) ^ (row & 7);
    Ag[i] = A + (size_t)(bx * 128 + row) * K + gch * 8;
    Bg[i] = Bw + (size_t)(by * 128 + row) * K + gch * 8;
    ldof[i] = c * 16;  // bytes
  }

#define GSTAGE(t, bsel)                                                        \
  do {                                                                         \
    char* lA = (char*)&ldsA[bsel][0];                                          \
    char* lB = (char*)&ldsB[bsel][0];                                          \
    _Pragma("unroll") for (int i = 0; i < 4; ++i)                              \
        gload16(Ag[i] + (size_t)(t) * 64, lA + ldof[i]);                       \
    _Pragma("unroll") for (int i = 0; i < 4; ++i)                              \
        gload16(Bg[i] + (size_t)(t) * 64, lB + ldof[i]);                       \
  } while (0)

  const int nst = K >> 6;  // 16
  int buf = 0;
  GSTAGE(0, 0);
  for (int t = 0; t < nst; ++t) {
    if (t < nst - 1) {
      GSTAGE(t + 1, buf ^ 1);
      asm volatile("s_waitcnt vmcnt(8)" ::: "memory");  // t's 8 loads done; t+1's stay in flight
    } else {
      asm volatile("s_waitcnt vmcnt(0)" ::: "memory");
    }
    __builtin_amdgcn_s_barrier();
    asm volatile("" ::: "memory");

#pragma unroll
    for (int kk = 0; kk < 2; ++kk) {
      bf16x8 af[4], bfm[4];
#pragma unroll
      for (int m = 0; m < 4; ++m) {
        const int row = wr * 64 + m * 16 + lr;
        const int pos = (kk * 4 + lg) ^ (row & 7);
        af[m] = *(const bf16x8*)(&ldsA[buf][0] + row * 64 + pos * 8);
      }
#pragma unroll
      for (int n = 0; n < 4; ++n) {
        const int row = wc * 64 + n * 16 + lr;
        const int pos = (kk * 4 + lg) ^ (row & 7);
        bfm[n] = *(const bf16x8*)(&ldsB[buf][0] + row * 64 + pos * 8);
      }
      __builtin_amdgcn_s_setprio(1);
#pragma unroll
      for (int m = 0; m < 4; ++m)
#pragma unroll
        for (int n = 0; n < 4; ++n)
          acc[m][n] = mfma16(af[m], bfm[n], acc[m][n]);
      __builtin_amdgcn_s_setprio(0);
    }

    asm volatile("s_waitcnt lgkmcnt(0)" ::: "memory");  // all LDS reads of buf retired
    __builtin_amdgcn_s_barrier();                       // before next stage overwrites buf
    asm volatile("" ::: "memory");
    buf ^= 1;
  }
#undef GSTAGE

  if constexpr (MODE == 0) {
    const int slot = (by * 128) >> 10;
    const int csIn = (by * 128) & 1023;
    // Q gets softmax scale folded in base-2 domain: 0.125 * log2(e)
    const float sc = (slot == 0) ? 0.18033688011112042f : (alphap[0] * halfp[0]);
#pragma unroll
    for (int m = 0; m < 4; ++m) {
      const int grow0 = bx * 128 + wr * 64 + m * 16 + lg * 4;
#pragma unroll
      for (int n = 0; n < 4; ++n) {
        const int gcol = csIn + wc * 64 + n * 16 + lr;
        const int h = gcol >> 6, d = gcol & 63;
#pragma unroll
        for (int j = 0; j < 4; ++j) {
          const int grow = grow0 + j;
          const int b = grow >> 10, nn = grow & 1023;
          const unsigned short u = f2bf(acc[m][n][j] * sc);
          if (slot == 0)      Qg[(((size_t)b * NH + h) * NSEQ + nn) * NHD + d] = u;
          else if (slot == 1) Kg[(((size_t)b * NH + h) * NKV + NP + nn) * NHD + d] = u;
          else                Vt[(((size_t)b * NH + h) * NHD + d) * NKV + NP + nn] = u;
        }
      }
    }
  } else {
#pragma unroll
    for (int m = 0; m < 4; ++m) {
      const int grow0 = bx * 128 + wr * 64 + m * 16 + lg * 4;
#pragma unroll
      for (int n = 0; n < 4; ++n) {
        const int gcol = by * 128 + wc * 64 + n * 16 + lr;
        const float bb = bias[gcol];
#pragma unroll
        for (int j = 0; j < 4; ++j)
          Cout[(size_t)(grow0 + j) * NC + gcol] = acc[m][n][j] + bb;
      }
    }
  }
}

// ---------------- flash attention (swapped QK^T, defer-max, 2-deep pipeline) ----------------
// flat grid 1024: bh = id&127 (XCD locality: bh%8 -> same XCD), qtile = id>>7
__global__ __launch_bounds__(256, 3)
void attn_fwd(const unsigned short* __restrict__ Qg, const unsigned short* __restrict__ Kg,
              const unsigned short* __restrict__ Vt, unsigned short* __restrict__ Oat) {
  __shared__ __align__(16) unsigned short Klds[2][64 * 64];
  __shared__ __align__(16) unsigned short Vlds[2][64 * 64];
  __shared__ __align__(16) unsigned short Plds[4 * 32 * 64];
  const int tid = threadIdx.x, lane = tid & 63, wv = tid >> 6;
  const int bh = blockIdx.x & 127;
  const int q0 = (blockIdx.x >> 7) * 128;
  const int lg = lane >> 4, lr = lane & 15;

  // Q as B-operand frags: lane holds Q[q = wv*32+nq*16+lr][k = kk*32+lg*8 ..+8]
  bf16x8 bq[2][2];
#pragma unroll
  for (int nq = 0; nq < 2; ++nq)
#pragma unroll
    for (int kk = 0; kk < 2; ++kk)
      bq[nq][kk] = *(const bf16x8*)(Qg + ((size_t)bh * NSEQ + q0 + wv * 32 + nq * 16 + lr) * NHD + kk * 32 + lg * 8);

  f32x4 oac[2][4] = {};
  float mrun[2] = {-1e30f, -1e30f};
  float lrun[2] = {0.f, 0.f};

  const int kr0 = tid >> 3, kc = tid & 7;
  const int sw = kc ^ (kr0 & 7);
  const unsigned short* Kgp = Kg + ((size_t)bh * NKV + kr0) * NHD + sw * 8;
  const unsigned short* Vgp = Vt + ((size_t)bh * NHD + kr0) * NKV + sw * 8;
  unsigned short* Pw = Plds + wv * 2048;

#define STAGE(t, bsel)                                                      \
  do {                                                                      \
    unsigned short* kb = &Klds[bsel][0] + wv * 512;                         \
    unsigned short* vb = &Vlds[bsel][0] + wv * 512;                         \
    gload16(Kgp + (size_t)(t) * 4096, kb);                                  \
    gload16(Kgp + (size_t)(t) * 4096 + 32 * NHD, kb + 2048);                \
    gload16(Vgp + (size_t)(t) * 64, vb);                                    \
    gload16(Vgp + (size_t)(t) * 64 + (size_t)32 * NKV, vb + 2048);          \
  } while (0)

  STAGE(0, 0);
  asm volatile("s_waitcnt vmcnt(0)" ::: "memory");
  __builtin_amdgcn_s_barrier();

  for (int t = 0; t < 17; ++t) {
    const int b = t & 1;
    if (t < 16) STAGE(t + 1, b ^ 1);

    // S^T = K Q^T : sa[mk][nq], lane holds k = mk*16+lg*4+j for q = nq*16+lr
    f32x4 sa[4][2] = {};
    __builtin_amdgcn_s_setprio(1);
#pragma unroll
    for (int kk = 0; kk < 2; ++kk) {
      bf16x8 ak[4];
#pragma unroll
      for (int mk = 0; mk < 4; ++mk) {
        const int row = mk * 16 + lr;
        const int cc = (kk * 4 + lg) ^ (row & 7);
        ak[mk] = *(const bf16x8*)(&Klds[b][0] + row * 64 + cc * 8);
      }
#pragma unroll
      for (int mk = 0; mk < 4; ++mk)
#pragma unroll
        for (int nq = 0; nq < 2; ++nq)
          sa[mk][nq] = mfma16(ak[mk], bq[nq][kk], sa[mk][nq]);
    }
    __builtin_amdgcn_s_setprio(0);

    // row-max per q (lane owns q = nq*16+lr across lg quarter of k)
    float tmx[2];
#pragma unroll
    for (int nq = 0; nq < 2; ++nq) {
      f32x4 m4 = sa[0][nq];
#pragma unroll
      for (int mk = 1; mk < 4; ++mk)
#pragma unroll
        for (int j = 0; j < 4; ++j) m4[j] = fmaxf(m4[j], sa[mk][nq][j]);
      float tm = fmaxf(fmaxf(m4[0], m4[1]), fmaxf(m4[2], m4[3]));
      tm = fmaxf(tm, __shfl_xor(tm, 16));
      tm = fmaxf(tm, __shfl_xor(tm, 32));
      tmx[nq] = tm;
    }
    // defer-max (T13): only rescale when max grows > 8 (log2 domain)
    const bool upd = !__all((tmx[0] <= mrun[0] + 8.f) && (tmx[1] <= mrun[1] + 8.f));
    if (upd) {
      const float nm0 = fmaxf(mrun[0], tmx[0]);
      const float nm1 = fmaxf(mrun[1], tmx[1]);
      const float e0 = __builtin_amdgcn_exp2f(mrun[0] - nm0);
      const float e1 = __builtin_amdgcn_exp2f(mrun[1] - nm1);
      mrun[0] = nm0; mrun[1] = nm1;
      lrun[0] *= e0; lrun[1] *= e1;
#pragma unroll
      for (int m = 0; m < 2; ++m)
#pragma unroll
        for (int j = 0; j < 4; ++j) {
          const float fe = __shfl(m ? e1 : e0, lg * 4 + j, 16);
#pragma unroll
          for (int df = 0; df < 4; ++df) oac[m][df][j] *= fe;
        }
    }
    // P = 2^(S - m), sum, packed store to per-wave LDS (chunk-XOR swizzle)
#pragma unroll
    for (int nq = 0; nq < 2; ++nq) {
#pragma unroll
      for (int mk = 0; mk < 4; ++mk)
#pragma unroll
        for (int j = 0; j < 4; ++j)
          sa[mk][nq][j] = __builtin_amdgcn_exp2f(sa[mk][nq][j] - mrun[nq]);
      f32x4 s4 = sa[0][nq];
#pragma unroll
      for (int mk = 1; mk < 4; ++mk)
#pragma unroll
        for (int j = 0; j < 4; ++j) s4[j] += sa[mk][nq][j];
      float s = (s4[0] + s4[1]) + (s4[2] + s4[3]);
      s += __shfl_xor(s, 16);
      s += __shfl_xor(s, 32);
      lrun[nq] += s;
      const int q = nq * 16 + lr;
#pragma unroll
      for (int mk = 0; mk < 4; ++mk) {
        const int c = mk * 2 + (lg >> 1);
        uint2 uu;
        uu.x = (unsigned)f2bf(sa[mk][nq][0]) | ((unsigned)f2bf(sa[mk][nq][1]) << 16);
        uu.y = (unsigned)f2bf(sa[mk][nq][2]) | ((unsigned)f2bf(sa[mk][nq][3]) << 16);
        *(uint2*)(Pw + q * 64 + ((c ^ (q & 7)) << 3) + (lg & 1) * 4) = uu;
      }
    }

    // O += P V : A = P rows q (16B contiguous after swizzle), B = V^T rows d
    __builtin_amdgcn_s_setprio(1);
#pragma unroll
    for (int kk = 0; kk < 2; ++kk) {
      bf16x8 bv[4], ap[2];
#pragma unroll
      for (int df = 0; df < 4; ++df) {
        const int d = df * 16 + lr;
        const int cc = (kk * 4 + lg) ^ (d & 7);
        bv[df] = *(const bf16x8*)(&Vlds[b][0] + d * 64 + cc * 8);
      }
#pragma unroll
      for (int m = 0; m < 2; ++m) {
        const int q = m * 16 + lr;
        const int pos = (kk * 4 + lg) ^ (q & 7);
        ap[m] = *(const bf16x8*)(Pw + q * 64 + pos * 8);
      }
#pragma unroll
      for (int m = 0; m < 2; ++m)
#pragma unroll
        for (int df = 0; df < 4; ++df)
          oac[m][df] = mfma16(ap[m], bv[df], oac[m][df]);
    }
    __builtin_amdgcn_s_setprio(0);

    asm volatile("s_waitcnt vmcnt(0)" ::: "memory");
    __builtin_amdgcn_s_barrier();
  }
#undef STAGE

  const int bidx = bh >> 4, h = bh & 15;
  const float l0 = 1.f / lrun[0], l1 = 1.f / lrun[1];
#pragma unroll
  for (int m = 0; m < 2; ++m) {
#pragma unroll
    for (int j = 0; j < 4; ++j) {
      const float fi = __shfl(m ? l1 : l0, lg * 4 + j, 16);
      const int row = q0 + wv * 32 + m * 16 + lg * 4 + j;
#pragma unroll
      for (int df = 0; df < 4; ++df) {
        const int col = h * 64 + df * 16 + lr;
        Oat[((size_t)bidx * NSEQ + row) * NC + col] = f2bf(oac[m][df][j] * fi);
      }
    }
  }
}

// ---------------- launch ----------------
extern "C" void kernel_launch(void* const* d_in, const int* in_sizes, int n_in,
                              void* d_out, int out_size, void* d_ws, size_t ws_size,
                              hipStream_t stream) {
  const float* x      = (const float*)d_in[0];
  const float* prompt = (const float*)d_in[1];
  const float* alpha  = (const float*)d_in[2];
  const float* halfa  = (const float*)d_in[3];
  const float* Wqkv   = (const float*)d_in[4];
  const float* Wproj  = (const float*)d_in[5];
  const float* bproj  = (const float*)d_in[6];
  float* out = (float*)d_out;

  unsigned short* ws    = (unsigned short*)d_ws;
  unsigned short* x_bf  = ws;
  unsigned short* w_bf  = x_bf + (size_t)8192 * 1024;
  unsigned short* wp_bf = w_bf + (size_t)3072 * 1024;
  unsigned short* Qg    = wp_bf + (size_t)1024 * 1024;
  unsigned short* Kg    = Qg + (size_t)NB * NH * NSEQ * NHD;
  unsigned short* Vt    = Kg + (size_t)NB * NH * NKV * NHD;
  unsigned short* Oat   = Vt + (size_t)NB * NH * NKV * NHD;

  pack_bf16<<<8192, 256, 0, stream>>>(x, x_bf, 2097152);
  pack_bf16<<<3072, 256, 0, stream>>>(Wqkv, w_bf, 786432);
  pack_bf16<<<1024, 256, 0, stream>>>(Wproj, wp_bf, 262144);
  prefix_pack<<<512, 256, 0, stream>>>(prompt, Kg, Vt, alpha);

  gemm_bt<0><<<dim3(64, 24), 256, 0, stream>>>(x_bf, w_bf, 1024, Qg, Kg, Vt, alpha, halfa,
                                               nullptr, nullptr);
  attn_fwd<<<1024, 256, 0, stream>>>(Qg, Kg, Vt, Oat);
  gemm_bt<1><<<dim3(64, 8), 256, 0, stream>>>(Oat, wp_bf, 1024, nullptr, nullptr, nullptr,
                                              nullptr, nullptr, out, bproj);
}